// Round 7
// baseline (191.045 us; speedup 1.0000x reference)
//
#include <hip/hip_runtime.h>

// ---- problem constants ----
#define KW 11
#define NB 2            // N * C
#define DI 96
#define HI 256
#define WI 256
#define DOUT 86
#define HOUT 246
#define WOUT 246
#define HT 32           // output tile height (2 pixels/thread vertically)
#define WT 16           // output tile width
#define DCH 4           // chunks along D
#define DPC 22          // output d per chunk (22,22,22,20)
#define RR 42           // HT + KW - 1 region rows
#define HSZ (HI * WI)
#define SSIM_C1 1e-4f
#define SSIM_C2 9e-4f
#define NBLK (16 * 8 * NB * DCH)    // 1024
// raw slice: 42 rows x [img1: 8 chunks | img2: 8 chunks] x 16B = 672 slots,
// padded to 768/slice. Chunk c of row r stored at slot c^(r&7) (XOR swizzle,
// applied on the DMA *source* so LDS dest stays lane-linear).
#define SL_SLOT 768
#define RAW_SLOT (2 * SL_SLOT)      // 1536 slots = 24576 B
#define NSTG 6                      // staging tasks per thread (1536/256)

typedef const unsigned int __attribute__((address_space(1)))* gp1_t;
typedef unsigned int __attribute__((address_space(3)))* lp3_t;
using f32x2 = __attribute__((ext_vector_type(2))) float;
using f32x4 = __attribute__((ext_vector_type(4))) float;

__device__ __forceinline__ void gl_lds16(const float* g, float* l) {
    __builtin_amdgcn_global_load_lds((gp1_t)(const void*)g, (lp3_t)(void*)l, 16, 0, 0);
}

__device__ __forceinline__ f32x2 pk_fma_s(f32x2 w, f32x2 x, f32x2 acc) {
    f32x2 d;
    asm("v_pk_fma_f32 %0, %1, %2, %3" : "=v"(d) : "s"(w), "v"(x), "v"(acc));
    return d;
}

__device__ __forceinline__ float rfl(float x) {
    return __int_as_float(__builtin_amdgcn_readfirstlane(__float_as_int(x)));
}

// Packed ring-buffer D-conv step, compile-time slot indices.
template<int J>
__device__ __forceinline__ void acc_step(
    f32x2 (&AB)[KW], f32x2 (&PQ)[KW], const f32x2 (&w2)[KW],
    f32x2 f12, f32x2 f34, bool emit, f32x2& o12, f32x2& o34)
{
    #pragma unroll
    for (int p = 0; p < KW; ++p) {
        const int s = (J - p + KW) % KW;   // compile-time
        AB[s] = pk_fma_s(w2[p], f12, AB[s]);
        PQ[s] = pk_fma_s(w2[p], f34, PQ[s]);
    }
    const int C = (J + 1) % KW;
    if (emit) { o12 = AB[C]; o34 = PQ[C]; }
    AB[C] = (f32x2){0.f, 0.f};
    PQ[C] = (f32x2){0.f, 0.f};
}

// NOTE: min-waves/EU = 2 (VGPR cap 256). (256,4) caps VGPRs at 64 -> massive
// spill (R4: 1.1 GB scratch writes, 3x slowdown). Keep 2.
static __global__ __launch_bounds__(256, 2) void ssim_main(
    const float* __restrict__ img1, const float* __restrict__ img2,
    const float* __restrict__ win, float* __restrict__ bsum)
{
    __shared__ __align__(16) float rawf[RAW_SLOT * 4];   // 24576 B
    __shared__ __align__(16) f32x4 A4[2][RR][WT + 1];    // 22848 B
    __shared__ float w1s[KW];
    __shared__ float tmpw[121];
    __shared__ float red[4];

    const int t = threadIdx.x;
    const int bz = blockIdx.z;            // n*4 + chunk
    const int n = bz >> 2, chunk = bz & 3;
    const int d0 = chunk * DPC;
    const int dpc = (DOUT - d0 < DPC) ? (DOUT - d0) : DPC;   // 22,22,22,20
    const int NIT = (dpc + KW) >> 1;      // 16 or 15 iters, 2 slices each
    const int h0 = blockIdx.y * HT, w0 = blockIdx.x * WT;

    // 1-D separable profile from marginal sums of the 3-D window.
    if (t < 121) {
        const int i = t / KW, j = t - i * KW;
        const float* wp = win + i * (KW * KW) + j * KW;
        float s = 0.f;
        #pragma unroll
        for (int m = 0; m < KW; ++m) s += wp[m];
        tmpw[t] = s;
    }
    __syncthreads();
    if (t < KW) {
        float s = 0.f;
        #pragma unroll
        for (int j = 0; j < KW; ++j) s += tmpw[t * KW + j];
        w1s[t] = s;
    }
    __syncthreads();
    f32x2 w2[KW];                          // wave-uniform -> SGPR pairs
    #pragma unroll
    for (int k = 0; k < KW; ++k) {
        const float ws = rfl(w1s[k]);
        w2[k] = (f32x2){ws, ws};
    }

    // ---- staging task setup: 6 tasks/thread, u = t + 256q in [0,1536) ----
    // slot u: sl = u/768, v = u%768, r = v>>4, half = (v>>3)&1, c = v&7.
    // slot c holds GLOBAL chunk c^(r&7)  (involution).
    const float* tp[NSTG];
    int tstr[NSTG];
    #pragma unroll
    for (int q = 0; q < NSTG; ++q) {
        const int u = t + 256 * q;
        const int sl = (u >= SL_SLOT) ? 1 : 0;
        const int v = u - sl * SL_SLOT;
        const int r = v >> 4;
        const int half = (v >> 3) & 1;
        const int cg = (v & 7) ^ (r & 7);       // global chunk index
        const int gh = h0 + r, gw0 = w0 + 4 * cg;
        const bool oob = (v >= 672) || (gh >= HI) || (gw0 >= WI);
        const float* base = half ? img2 : img1;
        tp[q] = oob ? img1
                    : base + ((long)(n * DI + d0 + sl) * HSZ + (long)gh * WI + gw0);
        tstr[q] = oob ? 0 : 2 * HSZ;            // 2 slices per iteration
    }
    float* const ldst = &rawf[4 * t];           // dest: lane-linear, +1024 floats/q

    // D-conv rings: 2 pixels/thread x (AB = (mu1,mu2), PQ = (E12, Ess)).
    f32x2 rAB0[KW], rPQ0[KW], rAB1[KW], rPQ1[KW];
    #pragma unroll
    for (int p = 0; p < KW; ++p) {
        rAB0[p] = (f32x2){0.f,0.f}; rPQ0[p] = (f32x2){0.f,0.f};
        rAB1[p] = (f32x2){0.f,0.f}; rPQ1[p] = (f32x2){0.f,0.f};
    }

    const int g = t >> 4, tx = t & 15;          // pixel rows 2g, 2g+1; col tx
    const bool validc = (w0 + tx) < WOUT;
    const bool valid0 = validc && (h0 + 2*g     < HOUT);
    const bool valid1 = validc && (h0 + 2*g + 1 < HOUT);
    float partial = 0.f;

    // Phase A: one 4-output W-conv task; u in [0,336) = 2 sl x 42 r x 4 cg.
    // Streaming form: per input col m, update all outputs o with k=m-o in [0,10].
    auto phaseA = [&](int u) {
        const int sl = (u >= 168) ? 1 : 0;
        const int v = u - sl * 168;
        const int r = v >> 2, cg = v & 3;
        const int rsw = r & 7;
        const float* rb = &rawf[sl * (SL_SLOT * 4) + r * 64];
        f32x2 s12[4] = {{0.f,0.f},{0.f,0.f},{0.f,0.f},{0.f,0.f}};
        f32x2 s34[4] = {{0.f,0.f},{0.f,0.f},{0.f,0.f},{0.f,0.f}};
        #pragma unroll
        for (int q = 0; q < 4; ++q) {
            const int ch4 = (((cg + q) ^ rsw) << 2);     // swizzled chunk base
            const f32x4 aq = *(const f32x4*)(rb + ch4);
            const f32x4 bq = *(const f32x4*)(rb + 32 + ch4);
            #pragma unroll
            for (int j = 0; j < 4; ++j) {
                const int m = 4 * q + j;                 // logical col c0+m
                if (m < 14) {
                    const float x = aq[j], y = bq[j];
                    const f32x2 pxy = (f32x2){x, y};
                    const f32x2 pts = (f32x2){x * y, fmaf(x, x, y * y)};
                    #pragma unroll
                    for (int o = 0; o < 4; ++o) {
                        const int k = m - o;             // compile-time
                        if (k >= 0 && k <= 10) {
                            s12[o] = pk_fma_s(w2[k], pxy, s12[o]);
                            s34[o] = pk_fma_s(w2[k], pts, s34[o]);
                        }
                    }
                }
            }
        }
        #pragma unroll
        for (int o = 0; o < 4; ++o)
            A4[sl][r][4 * cg + o] =
                (f32x4){s12[o].x, s12[o].y, s34[o].x, s34[o].y};
    };

    // ---- prologue: stage slices d0, d0+1 ----
    #pragma unroll
    for (int q = 0; q < NSTG; ++q) {
        gl_lds16(tp[q], ldst + 1024 * q);
        tp[q] += tstr[q];
    }
    __syncthreads();   // drains vmcnt -> raw ready

    int jj = 0;        // (2i) % 11
    for (int i = 0; i < NIT; ++i) {
        // ---- phase A: both slices' W-convs (336 tasks / 256 threads) ----
        phaseA(t);
        if (t < 80) phaseA(t + 256);
        __syncthreads();   // A4 ready; raw fully consumed

        // ---- issue staging for next slice pair (lands during phase B) ----
        if (i + 1 < NIT) {
            #pragma unroll
            for (int q = 0; q < NSTG; ++q) {
                gl_lds16(tp[q], ldst + 1024 * q);
                tp[q] += tstr[q];
            }
        }

        // ---- phase B: H-conv (sliding window, 2 pixels), ring x4, emit ----
        f32x2 f12[2][2] = {{{0.f,0.f},{0.f,0.f}},{{0.f,0.f},{0.f,0.f}}};
        f32x2 f34[2][2] = {{{0.f,0.f},{0.f,0.f}},{{0.f,0.f},{0.f,0.f}}};
        #pragma unroll
        for (int s = 0; s < 2; ++s) {
            #pragma unroll
            for (int k = 0; k < 12; ++k) {
                const f32x4 vv = A4[s][2 * g + k][tx];
                const f32x2 lo = (f32x2){vv.x, vv.y};
                const f32x2 hi = (f32x2){vv.z, vv.w};
                if (k < 11) {
                    f12[s][0] = pk_fma_s(w2[k], lo, f12[s][0]);
                    f34[s][0] = pk_fma_s(w2[k], hi, f34[s][0]);
                }
                if (k >= 1) {
                    f12[s][1] = pk_fma_s(w2[k-1], lo, f12[s][1]);
                    f34[s][1] = pk_fma_s(w2[k-1], hi, f34[s][1]);
                }
            }
        }

        const bool emit = (i >= 5);
        f32x2 o12[2][2], o34[2][2];
        #pragma unroll
        for (int s = 0; s < 2; ++s)
            #pragma unroll
            for (int p = 0; p < 2; ++p) { o12[s][p] = (f32x2){0.f,0.f}; o34[s][p] = (f32x2){0.f,0.f}; }

        switch (jj) {
            #define CASE2(J) case J: \
                acc_step<J>(rAB0, rPQ0, w2, f12[0][0], f34[0][0], emit, o12[0][0], o34[0][0]); \
                acc_step<J>(rAB1, rPQ1, w2, f12[0][1], f34[0][1], emit, o12[0][1], o34[0][1]); \
                acc_step<(J+1)%KW>(rAB0, rPQ0, w2, f12[1][0], f34[1][0], emit, o12[1][0], o34[1][0]); \
                acc_step<(J+1)%KW>(rAB1, rPQ1, w2, f12[1][1], f34[1][1], emit, o12[1][1], o34[1][1]); \
                break;
            CASE2(0) CASE2(1) CASE2(2) CASE2(3) CASE2(4) CASE2(5)
            CASE2(6) CASE2(7) CASE2(8) CASE2(9) CASE2(10)
            #undef CASE2
        }
        jj += 2; if (jj >= KW) jj -= KW;

        if (emit) {
            #pragma unroll
            for (int s = 0; s < 2; ++s) {
                #pragma unroll
                for (int p = 0; p < 2; ++p) {
                    if (p ? valid1 : valid0) {
                        const float mu1 = o12[s][p].x, mu2 = o12[s][p].y;
                        const float m11 = mu1 * mu1, m22 = mu2 * mu2, m12 = mu1 * mu2;
                        const float num = (2.f * m12 + SSIM_C1)
                                        * (2.f * (o34[s][p].x - m12) + SSIM_C2);
                        const float den = (m11 + m22 + SSIM_C1)
                                        * ((o34[s][p].y - m11 - m22) + SSIM_C2);
                        partial += num * __builtin_amdgcn_rcpf(den);
                    }
                }
            }
        }
        __syncthreads();   // staged raw complete + A4 consumed
    }

    // ---- block reduction ----
    #pragma unroll
    for (int off = 32; off >= 1; off >>= 1)
        partial += __shfl_down(partial, off, 64);
    if ((t & 63) == 0) red[t >> 6] = partial;
    __syncthreads();
    if (t == 0) {
        bsum[(blockIdx.z * gridDim.y + blockIdx.y) * gridDim.x + blockIdx.x]
            = red[0] + red[1] + red[2] + red[3];
    }
}

static __global__ __launch_bounds__(256) void ssim_reduce(
    const float* __restrict__ bsum, float* __restrict__ out)
{
    __shared__ double red[4];
    const int t = threadIdx.x;
    double s = 0.0;
    for (int i = t; i < NBLK; i += 256) s += (double)bsum[i];
    #pragma unroll
    for (int off = 32; off >= 1; off >>= 1)
        s += __shfl_down(s, off, 64);
    if ((t & 63) == 0) red[t >> 6] = s;
    __syncthreads();
    if (t == 0) {
        const double tot = red[0] + red[1] + red[2] + red[3];
        out[0] = (float)(tot / (double)((long)NB * DOUT * HOUT * WOUT));
    }
}

extern "C" void kernel_launch(void* const* d_in, const int* in_sizes, int n_in,
                              void* d_out, int out_size, void* d_ws, size_t ws_size,
                              hipStream_t stream)
{
    const float* img1 = (const float*)d_in[0];
    const float* img2 = (const float*)d_in[1];
    const float* win  = (const float*)d_in[2];
    float* out  = (float*)d_out;
    float* bsum = (float*)d_ws;   // 1024 floats = 4 KB scratch

    dim3 grid(16, 8, NB * DCH);   // W-tiles, H-tiles, n*DCH+chunk
    ssim_main<<<grid, 256, 0, stream>>>(img1, img2, win, bsum);
    ssim_reduce<<<1, 256, 0, stream>>>(bsum, out);
}

// Round 8
// 117.538 us; speedup vs baseline: 1.6254x; 1.6254x over previous
//
#include <hip/hip_runtime.h>

// ---- problem constants ----
#define KW 11
#define NB 2            // N * C
#define DI 96
#define HI 256
#define WI 256
#define DOUT 86
#define HOUT 246
#define WOUT 246
#define HT 16           // output tile height
#define WT 16           // output tile width
#define DCH 4           // chunks along D
#define DPC 22          // output d per chunk (22,22,22,20)
#define RR 26           // HT + KW - 1 region rows
#define HSZ (HI * WI)
#define SSIM_C1 1e-4f
#define SSIM_C2 9e-4f
#define NBLK (16 * 16 * NB * DCH)   // 2048
// raw slice: 32 rows (26 real) x [img1: 8 chunks | img2: 8 chunks] x 16B
// = 512 slots/slice; 2 slices = 1024 slots = 16 KB. Chunk c of row r lives
// at slot c^(r&7) (involution; applied on the DMA source, LDS dest linear).
#define SL_SLOT 512
#define NSTG 4                      // staging tasks per thread (1024/256)

typedef const unsigned int __attribute__((address_space(1)))* gp1_t;
typedef unsigned int __attribute__((address_space(3)))* lp3_t;
using f32x2 = __attribute__((ext_vector_type(2))) float;
using f32x4 = __attribute__((ext_vector_type(4))) float;

__device__ __forceinline__ void gl_lds16(const float* g, float* l) {
    __builtin_amdgcn_global_load_lds((gp1_t)(const void*)g, (lp3_t)(void*)l, 16, 0, 0);
}

// packed fp32 FMA, wave-uniform weight in SGPR pair.
__device__ __forceinline__ f32x2 pk_fma_s(f32x2 w, f32x2 x, f32x2 acc) {
    f32x2 d;
    asm("v_pk_fma_f32 %0, %1, %2, %3" : "=v"(d) : "s"(w), "v"(x), "v"(acc));
    return d;
}

__device__ __forceinline__ float rfl(float x) {
    return __int_as_float(__builtin_amdgcn_readfirstlane(__float_as_int(x)));
}

// Packed ring-buffer D-conv step, compile-time slot indices.
template<int J>
__device__ __forceinline__ void acc_step(
    f32x2 (&AB)[KW], f32x2 (&PQ)[KW], const f32x2 (&w2)[KW],
    f32x2 f12, f32x2 f34, bool emit, f32x2& o12, f32x2& o34)
{
    #pragma unroll
    for (int p = 0; p < KW; ++p) {
        const int s = (J - p + KW) % KW;   // compile-time
        AB[s] = pk_fma_s(w2[p], f12, AB[s]);
        PQ[s] = pk_fma_s(w2[p], f34, PQ[s]);
    }
    const int C = (J + 1) % KW;
    if (emit) { o12 = AB[C]; o34 = PQ[C]; }
    AB[C] = (f32x2){0.f, 0.f};
    PQ[C] = (f32x2){0.f, 0.f};
}

// NOTE: min-waves/EU = 2 (VGPR cap 256). (256,4) caps VGPRs at 64 -> massive
// spill (R4). Vertical coarsening (2 rings/thread) also spills (R7). Keep
// single ring set, cap 2.
static __global__ __launch_bounds__(256, 2) void ssim_main(
    const float* __restrict__ img1, const float* __restrict__ img2,
    const float* __restrict__ win, float* __restrict__ bsum)
{
    __shared__ __align__(16) float rawf[2 * SL_SLOT * 4];  // 16384 B
    __shared__ __align__(16) f32x4 A4[2][RR][WT + 1];      // 14144 B
    __shared__ float w1s[KW];
    __shared__ float tmpw[121];
    __shared__ float red[4];

    const int t = threadIdx.x;
    const int bz = blockIdx.z;            // n*4 + chunk
    const int n = bz >> 2, chunk = bz & 3;
    const int d0 = chunk * DPC;
    const int dpc = (DOUT - d0 < DPC) ? (DOUT - d0) : DPC;   // 22,22,22,20
    const int NIT = (dpc + KW - 1) >> 1;   // 16 or 15 iters, 2 slices each
    const int h0 = blockIdx.y * HT, w0 = blockIdx.x * WT;

    // 1-D separable profile from marginal sums of the 3-D window.
    if (t < 121) {
        const int i = t / KW, j = t - i * KW;
        const float* wp = win + i * (KW * KW) + j * KW;
        float s = 0.f;
        #pragma unroll
        for (int m = 0; m < KW; ++m) s += wp[m];
        tmpw[t] = s;
    }
    __syncthreads();
    if (t < KW) {
        float s = 0.f;
        #pragma unroll
        for (int j = 0; j < KW; ++j) s += tmpw[t * KW + j];
        w1s[t] = s;
    }
    __syncthreads();
    f32x2 w2[KW];                          // wave-uniform -> SGPR pairs
    #pragma unroll
    for (int k = 0; k < KW; ++k) {
        const float ws = rfl(w1s[k]);
        w2[k] = (f32x2){ws, ws};
    }

    // ---- staging task setup: 4 tasks/thread, u = t + 256q in [0,1024) ----
    // slot u: sl = u>>9, v = u&511, r = v>>4 (26 real), half = (v>>3)&1,
    // c = v&7; slot c holds GLOBAL chunk c^(r&7).
    const float* tp[NSTG];
    int tstr[NSTG];
    #pragma unroll
    for (int q = 0; q < NSTG; ++q) {
        const int u = t + 256 * q;
        const int sl = u >> 9;
        const int v = u & 511;
        const int r = v >> 4;
        const int half = (v >> 3) & 1;
        const int cg = (v & 7) ^ (r & 7);       // global chunk index
        const int gh = h0 + r, gw0 = w0 + 4 * cg;
        const bool oob = (r >= RR) || (gh >= HI) || (gw0 >= WI);
        const float* base = half ? img2 : img1;
        tp[q] = oob ? img1
                    : base + ((long)(n * DI + d0 + sl) * HSZ + (long)gh * WI + gw0);
        tstr[q] = oob ? 0 : 2 * HSZ;            // 2 slices per iteration
    }
    float* const ldst = &rawf[4 * t];           // lane-linear dest, +1024/q

    // Packed D-conv rings: AB = (mu1,mu2), PQ = (E12, Ess).
    f32x2 rAB[KW], rPQ[KW];
    #pragma unroll
    for (int p = 0; p < KW; ++p) { rAB[p] = (f32x2){0.f,0.f}; rPQ[p] = (f32x2){0.f,0.f}; }

    const int ty = t >> 4, tx = t & 15;
    const bool valid = (h0 + ty < HOUT) && (w0 + tx < WOUT);
    float partial = 0.f;

    // Phase A: one 4-output W-conv task; u in [0,208) = 2 sl x 26 r x 4 cg.
    // Streaming: per input col m (rel to 4cg), update outputs o, k=m-o in [0,10].
    auto phaseA = [&](int u) {
        const int sl = (u >= 104) ? 1 : 0;
        const int v = u - sl * 104;
        const int r = v >> 2, cg = v & 3;
        const int rsw = r & 7;
        const float* rb = &rawf[sl * (SL_SLOT * 4) + r * 64];
        f32x2 s12[4] = {{0.f,0.f},{0.f,0.f},{0.f,0.f},{0.f,0.f}};
        f32x2 s34[4] = {{0.f,0.f},{0.f,0.f},{0.f,0.f},{0.f,0.f}};
        #pragma unroll
        for (int q = 0; q < 4; ++q) {
            const int ch4 = (((cg + q) ^ rsw) << 2);     // swizzled chunk base
            const f32x4 aq = *(const f32x4*)(rb + ch4);
            const f32x4 bq = *(const f32x4*)(rb + 32 + ch4);
            #pragma unroll
            for (int j = 0; j < 4; ++j) {
                const int m = 4 * q + j;                 // rel col
                if (m < 14) {
                    const float x = aq[j], y = bq[j];
                    const f32x2 pxy = (f32x2){x, y};
                    const f32x2 pts = (f32x2){x * y, fmaf(x, x, y * y)};
                    #pragma unroll
                    for (int o = 0; o < 4; ++o) {
                        const int k = m - o;             // compile-time
                        if (k >= 0 && k <= 10) {
                            s12[o] = pk_fma_s(w2[k], pxy, s12[o]);
                            s34[o] = pk_fma_s(w2[k], pts, s34[o]);
                        }
                    }
                }
            }
        }
        #pragma unroll
        for (int o = 0; o < 4; ++o)
            A4[sl][r][4 * cg + o] = (f32x4){s12[o].x, s12[o].y, s34[o].x, s34[o].y};
    };

    // ---- prologue: stage slices d0, d0+1 ----
    #pragma unroll
    for (int q = 0; q < NSTG; ++q) {
        gl_lds16(tp[q], ldst + 1024 * q);
        tp[q] += tstr[q];
    }
    __syncthreads();   // drains vmcnt -> raw ready

    int jj = 0;        // (2i) % 11
    for (int i = 0; i < NIT; ++i) {
        // ---- phase A: both slices' W-convs (208 tasks) ----
        if (t < 208) phaseA(t);
        __syncthreads();   // A4 ready; raw fully consumed

        // ---- issue staging for next slice pair (lands during phase B) ----
        if (i + 1 < NIT) {
            #pragma unroll
            for (int q = 0; q < NSTG; ++q) {
                gl_lds16(tp[q], ldst + 1024 * q);
                tp[q] += tstr[q];
            }
        }

        // ---- phase B: packed H-conv both slices, ring x2, emit x2 ----
        f32x2 fa12={0.f,0.f}, fa34={0.f,0.f}, fb12={0.f,0.f}, fb34={0.f,0.f};
        #pragma unroll
        for (int kh = 0; kh < KW; ++kh) {
            const f32x4 va = A4[0][ty + kh][tx];
            const f32x4 vb = A4[1][ty + kh][tx];
            fa12 = pk_fma_s(w2[kh], (f32x2){va.x, va.y}, fa12);
            fa34 = pk_fma_s(w2[kh], (f32x2){va.z, va.w}, fa34);
            fb12 = pk_fma_s(w2[kh], (f32x2){vb.x, vb.y}, fb12);
            fb34 = pk_fma_s(w2[kh], (f32x2){vb.z, vb.w}, fb34);
        }

        const bool emit = (i >= 5);
        f32x2 oa12={0.f,0.f}, oa34={0.f,0.f}, ob12={0.f,0.f}, ob34={0.f,0.f};
        switch (jj) {
            #define CASE2(J) case J: \
                acc_step<J>(rAB, rPQ, w2, fa12, fa34, emit, oa12, oa34); \
                acc_step<(J+1)%KW>(rAB, rPQ, w2, fb12, fb34, emit, ob12, ob34); \
                break;
            CASE2(0) CASE2(1) CASE2(2) CASE2(3) CASE2(4) CASE2(5)
            CASE2(6) CASE2(7) CASE2(8) CASE2(9) CASE2(10)
            #undef CASE2
        }
        jj += 2; if (jj >= KW) jj -= KW;

        if (emit && valid) {
            {
                const float mu1 = oa12.x, mu2 = oa12.y;
                const float m11 = mu1 * mu1, m22 = mu2 * mu2, m12 = mu1 * mu2;
                const float num = (2.f * m12 + SSIM_C1) * (2.f * (oa34.x - m12) + SSIM_C2);
                const float den = (m11 + m22 + SSIM_C1) * ((oa34.y - m11 - m22) + SSIM_C2);
                partial += num * __builtin_amdgcn_rcpf(den);
            }
            {
                const float mu1 = ob12.x, mu2 = ob12.y;
                const float m11 = mu1 * mu1, m22 = mu2 * mu2, m12 = mu1 * mu2;
                const float num = (2.f * m12 + SSIM_C1) * (2.f * (ob34.x - m12) + SSIM_C2);
                const float den = (m11 + m22 + SSIM_C1) * ((ob34.y - m11 - m22) + SSIM_C2);
                partial += num * __builtin_amdgcn_rcpf(den);
            }
        }
        __syncthreads();   // staged raw complete + A4 consumed
    }

    // ---- block reduction ----
    #pragma unroll
    for (int off = 32; off >= 1; off >>= 1)
        partial += __shfl_down(partial, off, 64);
    if ((t & 63) == 0) red[t >> 6] = partial;
    __syncthreads();
    if (t == 0) {
        bsum[(blockIdx.z * gridDim.y + blockIdx.y) * gridDim.x + blockIdx.x]
            = red[0] + red[1] + red[2] + red[3];
    }
}

static __global__ __launch_bounds__(256) void ssim_reduce(
    const float* __restrict__ bsum, float* __restrict__ out)
{
    __shared__ double red[4];
    const int t = threadIdx.x;
    double s = 0.0;
    for (int i = t; i < NBLK; i += 256) s += (double)bsum[i];
    #pragma unroll
    for (int off = 32; off >= 1; off >>= 1)
        s += __shfl_down(s, off, 64);
    if ((t & 63) == 0) red[t >> 6] = s;
    __syncthreads();
    if (t == 0) {
        const double tot = red[0] + red[1] + red[2] + red[3];
        out[0] = (float)(tot / (double)((long)NB * DOUT * HOUT * WOUT));
    }
}

extern "C" void kernel_launch(void* const* d_in, const int* in_sizes, int n_in,
                              void* d_out, int out_size, void* d_ws, size_t ws_size,
                              hipStream_t stream)
{
    const float* img1 = (const float*)d_in[0];
    const float* img2 = (const float*)d_in[1];
    const float* win  = (const float*)d_in[2];
    float* out  = (float*)d_out;
    float* bsum = (float*)d_ws;   // 2048 floats = 8 KB scratch

    dim3 grid(16, 16, NB * DCH);
    ssim_main<<<grid, 256, 0, stream>>>(img1, img2, win, bsum);
    ssim_reduce<<<1, 256, 0, stream>>>(bsum, out);
}